// Round 9
// baseline (115.899 us; speedup 1.0000x reference)
//
#include <hip/hip_runtime.h>
#include <hip/hip_bf16.h>

typedef __bf16 bf16x8 __attribute__((ext_vector_type(8)));
typedef float  f32x4  __attribute__((ext_vector_type(4)));

#define IN_F   4096
#define OUT_F  4096
#define RANK   32
#define CF     128            // features per K1 chunk
#define NCH    (IN_F / CF)    // 32 chunks

__device__ __forceinline__ bf16x8 cvt8(float4 a, float4 b) {
    bf16x8 r;
    r[0] = (__bf16)a.x; r[1] = (__bf16)a.y; r[2] = (__bf16)a.z; r[3] = (__bf16)a.w;
    r[4] = (__bf16)b.x; r[5] = (__bf16)b.y; r[6] = (__bf16)b.z; r[7] = (__bf16)b.w;
    return r;
}

// async global->LDS, 16 B/lane: LDS dest = uniform base + lane*16,
// global src = per-lane address (pre-permuted to match fragment layout).
__device__ __forceinline__ void gl_lds16(const float* g, void* l) {
    __builtin_amdgcn_global_load_lds(
        (const __attribute__((address_space(1))) char*)g,
        (__attribute__((address_space(3))) char*)l, 16, 0, 0);
}

// ---------------- Kernel 1: H = (X @ V^T) * S ----------------
// 512 blocks x 256 thr (4 waves). 16 tokens/block, 32 chunks of 128 feats.
// TRIPLE-buffered LDS, 2-chunk-deep prefetch, counted vmcnt + RAW s_barrier
// (never vmcnt(0) in the main loop — __syncthreads would drain the prefetch).
// Per wave per chunk: 6 global_load_lds (1 KB each); steady-state 12-18
// loads outstanding per wave -> continuous HBM pressure.
__global__ __launch_bounds__(256, 2)
void lora_h(const float* __restrict__ X, const float* __restrict__ S,
            const float* __restrict__ V, float* __restrict__ H)
{
    __shared__ float4 XB[3][4][2][64];      // [buf][s][h][lane]  24 KB
    __shared__ float4 VB[3][2][4][2][64];   // [buf][rh][s][h][lane] 48 KB
    __shared__ float  Hp[4][16][17];        // per-wave partials

    const int tid  = threadIdx.x;
    const int wave = tid >> 6;
    const int lane = tid & 63;
    const int r    = lane & 15;
    const int kg   = lane >> 4;
    const int t0   = blockIdx.x * 16;

    const int rh = wave & 1;
    const int fs = wave >> 1;

    const size_t xrow = (size_t)(t0 + r) * IN_F;
    const int    sub  = kg * 4;

    // stage chunk c into buffer nb: 24 x 1KB instructions, 6 per wave
    auto stage = [&](int c, int nb) {
        const int fc = c * CF;
        #pragma unroll
        for (int t = 0; t < 6; ++t) {
            const int inst = wave * 6 + t;
            if (inst < 8) {                 // X: (s, h)
                const int s = inst >> 1, h2 = inst & 1;
                gl_lds16(X + xrow + fc + s * 32 + h2 * 16 + sub,
                         (void*)&XB[nb][s][h2][0]);
            } else {                        // V: (vrh, s, h)
                const int v = inst - 8;
                const int vrh = v >> 3, s = (v >> 1) & 3, h2 = v & 1;
                gl_lds16(V + (size_t)(vrh * 16 + r) * IN_F + fc + s * 32 + h2 * 16 + sub,
                         (void*)&VB[nb][vrh][s][h2][0]);
            }
        }
    };

    const int h  = kg >> 1;                 // half holding floats kg*8..+8
    const int qb = (kg & 1) * 2;

    f32x4 acc = {0.f, 0.f, 0.f, 0.f};

    auto compute = [&](int cur) {
        #pragma unroll
        for (int s2 = 0; s2 < 2; ++s2) {
            const int s = fs * 2 + s2;
            float4 x0 = *(const float4*)&XB[cur][s][h][qb * 16 + r];
            float4 x1 = *(const float4*)&XB[cur][s][h][(qb + 1) * 16 + r];
            float4 v0 = *(const float4*)&VB[cur][rh][s][h][qb * 16 + r];
            float4 v1 = *(const float4*)&VB[cur][rh][s][h][(qb + 1) * 16 + r];
            acc = __builtin_amdgcn_mfma_f32_16x16x32_bf16(
                      cvt8(x0, x1), cvt8(v0, v1), acc, 0, 0, 0);
        }
    };

    stage(0, 0);
    stage(1, 1);

    for (int c = 0; c < NCH - 2; ++c) {
        stage(c + 2, (c + 2) % 3);
        asm volatile("s_waitcnt vmcnt(12)" ::: "memory");  // chunk c landed; c+1,c+2 in flight
        __builtin_amdgcn_s_barrier();
        __builtin_amdgcn_sched_barrier(0);
        compute(c % 3);
        __builtin_amdgcn_s_barrier();       // all waves done reading buf before re-stage
    }
    // peeled tail: c = NCH-2, NCH-1
    asm volatile("s_waitcnt vmcnt(6)" ::: "memory");
    __builtin_amdgcn_s_barrier();
    __builtin_amdgcn_sched_barrier(0);
    compute((NCH - 2) % 3);
    __builtin_amdgcn_s_barrier();
    asm volatile("s_waitcnt vmcnt(0)" ::: "memory");
    __builtin_amdgcn_s_barrier();
    __builtin_amdgcn_sched_barrier(0);
    compute((NCH - 1) % 3);

    // D: n(rank-in-half) = lane&15, m(token) = kg*4+j
    #pragma unroll
    for (int j = 0; j < 4; ++j) Hp[wave][kg * 4 + j][r] = acc[j];
    __syncthreads();

    // combine fs-halves, apply S (SCALING == 1.0 folded)
    for (int i = tid; i < 16 * RANK; i += 256) {
        const int tok = i >> 5, rr = i & 31;
        const int rhh = rr >> 4, ri = rr & 15;
        const float s = Hp[rhh][tok][ri] + Hp[2 + rhh][tok][ri];
        H[(size_t)(t0 + tok) * RANK + rr] = s * S[rr];
    }
}

// ---------------- Kernel 2: Out = H @ U^T (UNCHANGED from R8) ----------------
__global__ __launch_bounds__(256, 4)
void lora_out(const float* __restrict__ H, const float* __restrict__ U,
              float* __restrict__ Out)
{
    __shared__ float Hs[128][33];

    const int tid  = threadIdx.x;
    const int wave = tid >> 6;
    const int lane = tid & 63;
    const int r    = lane & 15;
    const int kg   = lane >> 4;

    const int tt = blockIdx.x >> 6;
    const int cq = blockIdx.x & 63;
    const int t0 = tt * 128;
    const int c0 = cq * 64;

    float4 ua[4][2];
    #pragma unroll
    for (int b = 0; b < 4; ++b) {
        const float4* up = reinterpret_cast<const float4*>(
            U + (size_t)(c0 + b * 16 + r) * RANK + kg * 8);
        ua[b][0] = up[0];
        ua[b][1] = up[1];
    }

    const float4* hsrc = reinterpret_cast<const float4*>(H + (size_t)t0 * RANK);
    #pragma unroll
    for (int k = 0; k < 4; ++k) {
        const int fidx = tid + k * 256;
        float4 v = hsrc[fidx];
        const int tok = fidx >> 3;
        const int rr  = (fidx & 7) * 4;
        Hs[tok][rr] = v.x; Hs[tok][rr + 1] = v.y;
        Hs[tok][rr + 2] = v.z; Hs[tok][rr + 3] = v.w;
    }
    __syncthreads();

    bf16x8 ub[4];
    #pragma unroll
    for (int b = 0; b < 4; ++b) ub[b] = cvt8(ua[b][0], ua[b][1]);

    #pragma unroll
    for (int ai = 0; ai < 2; ++ai) {
        const int a = wave + ai * 4;
        bf16x8 hb;
        #pragma unroll
        for (int j = 0; j < 8; ++j) hb[j] = (__bf16)Hs[a * 16 + r][kg * 8 + j];
        float* orow = Out + (size_t)(t0 + a * 16 + r) * OUT_F + c0 + kg * 4;
        #pragma unroll
        for (int b = 0; b < 4; ++b) {
            f32x4 d = {0.f, 0.f, 0.f, 0.f};
            d = __builtin_amdgcn_mfma_f32_16x16x32_bf16(ub[b], hb, d, 0, 0, 0);
            *reinterpret_cast<float4*>(orow + b * 16) = *reinterpret_cast<float4*>(&d);
        }
    }
}

extern "C" void kernel_launch(void* const* d_in, const int* in_sizes, int n_in,
                              void* d_out, int out_size, void* d_ws, size_t ws_size,
                              hipStream_t stream) {
    const float* X = (const float*)d_in[0];
    const float* U = (const float*)d_in[1];
    const float* S = (const float*)d_in[2];
    const float* V = (const float*)d_in[3];
    float* Out = (float*)d_out;
    float* Hws = (float*)d_ws;              // H: 8192 x 32 fp32 = 1 MB

    lora_h  <<<512,  256, 0, stream>>>(X, S, V, Hws);
    // K2 launched TWICE (idempotent) for timing attribution:
    // dur(this round) = K1' + 2*K2 ; next round single-launch solves K1', K2.
    lora_out<<<4096, 256, 0, stream>>>(Hws, U, Out);
    lora_out<<<4096, 256, 0, stream>>>(Hws, U, Out);
}

// Round 10
// 70.727 us; speedup vs baseline: 1.6387x; 1.6387x over previous
//
#include <hip/hip_runtime.h>
#include <hip/hip_bf16.h>

typedef __bf16 bf16x8 __attribute__((ext_vector_type(8)));
typedef float  f32x4  __attribute__((ext_vector_type(4)));

#define IN_F   4096
#define OUT_F  4096
#define RANK   32

__device__ __forceinline__ bf16x8 cvt8(float4 a, float4 b) {
    bf16x8 r;
    r[0] = (__bf16)a.x; r[1] = (__bf16)a.y; r[2] = (__bf16)a.z; r[3] = (__bf16)a.w;
    r[4] = (__bf16)b.x; r[5] = (__bf16)b.y; r[6] = (__bf16)b.z; r[7] = (__bf16)b.w;
    return r;
}

__device__ __forceinline__ void gl_lds16(const float* g, void* l) {
    __builtin_amdgcn_global_load_lds(
        (const __attribute__((address_space(1))) char*)g,
        (__attribute__((address_space(3))) char*)l, 16, 0, 0);
}

// ---------------- Kernel 1: Hpart[ks] = X @ V^T over k-quarter ----------------
// grid (128, KS), 256 thr (4 waves). Block: 64 tokens x (IN_F/KS) feats in
// 64-feat double-buffered chunks (X 16KB + V 8KB = 24 x 1KB global_load_lds).
// V traffic amortized over 64 tokens (was 16): logical bytes 384->192 MB.
// Chunk order staggered by blockIdx.x to decorrelate column windows chip-wide.
template <int KS>
__global__ __launch_bounds__(256, 2)
void lora_h(const float* __restrict__ X, const float* __restrict__ S,
            const float* __restrict__ V, float* __restrict__ Hpart)
{
    constexpr int F    = IN_F / KS;     // feats per block
    constexpr int NCHK = F / 64;        // 64-feat chunks

    __shared__ float4 XB[2][4][2][2][64];  // [buf][tt][s][h][lane] 32 KB
    __shared__ float4 VB[2][2][2][2][64];  // [buf][rh][s][h][lane] 16 KB
    __shared__ float  Hp[4][64][17];       // per-wave partials     17 KB

    const int tid  = threadIdx.x;
    const int wave = tid >> 6;
    const int lane = tid & 63;
    const int r    = lane & 15;
    const int kg   = lane >> 4;

    const int rh = wave & 1;            // rank half this wave computes
    const int fs = wave >> 1;           // K-step half (s index)

    const int t0    = blockIdx.x * 64;
    const int fbase = blockIdx.y * F;

    // stage chunk (logical id c) into buffer nb: 24 instrs, 6 per wave
    auto stage = [&](int c, int nb) {
        const int fc = fbase + ((c + blockIdx.x) & (NCHK - 1)) * 64;
        #pragma unroll
        for (int t = 0; t < 6; ++t) {
            const int inst = wave * 6 + t;
            if (inst < 16) {            // X: tt, s, h
                const int tt = inst >> 2, s = (inst >> 1) & 1, h2 = inst & 1;
                gl_lds16(X + (size_t)(t0 + tt * 16 + r) * IN_F
                           + fc + s * 32 + h2 * 16 + kg * 4,
                         (void*)&XB[nb][tt][s][h2][0]);
            } else {                    // V: rh, s, h
                const int v = inst - 16;
                const int vr = v >> 2, s = (v >> 1) & 1, h2 = v & 1;
                gl_lds16(V + (size_t)(vr * 16 + r) * IN_F
                           + fc + s * 32 + h2 * 16 + kg * 4,
                         (void*)&VB[nb][vr][s][h2][0]);
            }
        }
    };

    const int h  = kg >> 1;             // 16-float half holding feats kg*8..+8
    const int qb = (kg & 1) * 2;        // first float4 slot in that half

    f32x4 acc[4] = {};                  // one per 16-token tile

    auto compute = [&](int cur) {
        float4 v0 = *(const float4*)&VB[cur][rh][fs][h][qb * 16 + r];
        float4 v1 = *(const float4*)&VB[cur][rh][fs][h][(qb + 1) * 16 + r];
        bf16x8 vb = cvt8(v0, v1);
        #pragma unroll
        for (int tt = 0; tt < 4; ++tt) {
            float4 x0 = *(const float4*)&XB[cur][tt][fs][h][qb * 16 + r];
            float4 x1 = *(const float4*)&XB[cur][tt][fs][h][(qb + 1) * 16 + r];
            // A = X (m = token), B = V (n = rank-in-half); K = 32 feats
            acc[tt] = __builtin_amdgcn_mfma_f32_16x16x32_bf16(
                          cvt8(x0, x1), vb, acc[tt], 0, 0, 0);
        }
    };

    stage(0, 0);
    for (int c = 0; c < NCHK; ++c) {
        const int cur = c & 1;
        if (c + 1 < NCHK) {
            stage(c + 1, cur ^ 1);
            asm volatile("s_waitcnt vmcnt(6)" ::: "memory");  // chunk c landed, c+1 in flight
        } else {
            asm volatile("s_waitcnt vmcnt(0)" ::: "memory");
        }
        __builtin_amdgcn_s_barrier();
        __builtin_amdgcn_sched_barrier(0);
        compute(cur);
        __builtin_amdgcn_s_barrier();   // all waves done reading buf before re-stage
    }

    // D: token = tt*16 + kg*4 + j, rank-in-half = lane&15
    #pragma unroll
    for (int tt = 0; tt < 4; ++tt)
        #pragma unroll
        for (int j = 0; j < 4; ++j)
            Hp[wave][tt * 16 + kg * 4 + j][r] = acc[tt][j];
    __syncthreads();

    // combine fs halves, apply S, write k-quarter partial
    float* dst = Hpart + ((size_t)blockIdx.y * 8192 + t0) * RANK;
    for (int i = tid; i < 64 * RANK; i += 256) {
        const int tok = i >> 5, rr = i & 31;
        const int rhh = rr >> 4, ri = rr & 15;
        const float s = Hp[rhh][tok][ri] + Hp[2 + rhh][tok][ri];
        dst[i] = s * S[rr];             // SCALING == 1.0 folded
    }
}

// ---------------- Kernel 2: Out = H @ U^T (R8 structure + nks reduce) ----------------
template <int NKS>
__global__ __launch_bounds__(256, 4)
void lora_out(const float* __restrict__ Hpart, const float* __restrict__ U,
              float* __restrict__ Out)
{
    __shared__ float Hs[128][33];

    const int tid  = threadIdx.x;
    const int wave = tid >> 6;
    const int lane = tid & 63;
    const int r    = lane & 15;
    const int kg   = lane >> 4;

    const int tt = blockIdx.x >> 6;
    const int cq = blockIdx.x & 63;
    const int t0 = tt * 128;
    const int c0 = cq * 64;

    float4 ua[4][2];
    #pragma unroll
    for (int b = 0; b < 4; ++b) {
        const float4* up = reinterpret_cast<const float4*>(
            U + (size_t)(c0 + b * 16 + r) * RANK + kg * 8);
        ua[b][0] = up[0];
        ua[b][1] = up[1];
    }

    // H tile -> LDS, reducing NKS k-partials
    #pragma unroll
    for (int k4 = 0; k4 < 4; ++k4) {
        const int fidx = tid + k4 * 256;    // float4 idx within [128][32] tile
        float4 v = {0.f, 0.f, 0.f, 0.f};
        #pragma unroll
        for (int k = 0; k < NKS; ++k) {
            const float4* hp = reinterpret_cast<const float4*>(
                Hpart + ((size_t)k * 8192 + t0) * RANK);
            float4 p = hp[fidx];
            v.x += p.x; v.y += p.y; v.z += p.z; v.w += p.w;
        }
        const int tok = fidx >> 3;
        const int rr  = (fidx & 7) * 4;
        Hs[tok][rr] = v.x; Hs[tok][rr + 1] = v.y;
        Hs[tok][rr + 2] = v.z; Hs[tok][rr + 3] = v.w;
    }
    __syncthreads();

    bf16x8 ub[4];
    #pragma unroll
    for (int b = 0; b < 4; ++b) ub[b] = cvt8(ua[b][0], ua[b][1]);

    #pragma unroll
    for (int ai = 0; ai < 2; ++ai) {
        const int a = wave + ai * 4;
        bf16x8 hb;
        #pragma unroll
        for (int j = 0; j < 8; ++j) hb[j] = (__bf16)Hs[a * 16 + r][kg * 8 + j];
        float* orow = Out + (size_t)(t0 + a * 16 + r) * OUT_F + c0 + kg * 4;
        #pragma unroll
        for (int b = 0; b < 4; ++b) {
            f32x4 d = {0.f, 0.f, 0.f, 0.f};
            d = __builtin_amdgcn_mfma_f32_16x16x32_bf16(ub[b], hb, d, 0, 0, 0);
            *reinterpret_cast<float4*>(orow + b * 16) = *reinterpret_cast<float4*>(&d);
        }
    }
}

extern "C" void kernel_launch(void* const* d_in, const int* in_sizes, int n_in,
                              void* d_out, int out_size, void* d_ws, size_t ws_size,
                              hipStream_t stream) {
    const float* X = (const float*)d_in[0];
    const float* U = (const float*)d_in[1];
    const float* S = (const float*)d_in[2];
    const float* V = (const float*)d_in[3];
    float* Out   = (float*)d_out;
    float* Hpart = (float*)d_ws;

    if (ws_size >= (size_t)4 * 1024 * 1024) {
        lora_h<4><<<dim3(128, 4), 256, 0, stream>>>(X, S, V, Hpart);
        lora_out<4><<<4096, 256, 0, stream>>>(Hpart, U, Out);
    } else {
        lora_h<1><<<dim3(128, 1), 256, 0, stream>>>(X, S, V, Hpart);
        lora_out<1><<<4096, 256, 0, stream>>>(Hpart, U, Out);
    }
}

// Round 11
// 68.321 us; speedup vs baseline: 1.6964x; 1.0352x over previous
//
#include <hip/hip_runtime.h>
#include <hip/hip_bf16.h>

typedef __bf16 bf16x8 __attribute__((ext_vector_type(8)));
typedef float  f32x4  __attribute__((ext_vector_type(4)));

#define IN_F   4096
#define OUT_F  4096
#define RANK   32

__device__ __forceinline__ bf16x8 cvt8(float4 a, float4 b) {
    bf16x8 r;
    r[0] = (__bf16)a.x; r[1] = (__bf16)a.y; r[2] = (__bf16)a.z; r[3] = (__bf16)a.w;
    r[4] = (__bf16)b.x; r[5] = (__bf16)b.y; r[6] = (__bf16)b.z; r[7] = (__bf16)b.w;
    return r;
}

__device__ __forceinline__ void gl_lds16(const float* g, void* l) {
    __builtin_amdgcn_global_load_lds(
        (const __attribute__((address_space(1))) char*)g,
        (__attribute__((address_space(3))) char*)l, 16, 0, 0);
}

// ---------------- Kernel 1: Hpart[ks] = (X @ V^T) * S over k-slice ----------------
// grid (128, KS), 256 thr (4 waves). Block: 64 tokens x (IN_F/KS) feats,
// 64-feat chunks, TRIPLE-buffered (72 KB LDS, 2 blocks/CU), stage-before-wait
// so vmcnt(12) keeps 2 chunks (48 KB/block) in flight at the wait point.
// Wave owns 16 tokens x ALL 32 ranks (acc[2]) -> no cross-wave combine, no Hp LDS.
template <int KS>
__global__ __launch_bounds__(256, 2)
void lora_h(const float* __restrict__ X, const float* __restrict__ S,
            const float* __restrict__ V, float* __restrict__ Hpart)
{
    constexpr int F    = IN_F / KS;
    constexpr int NCHK = F / 64;

    __shared__ float4 XB[3][4][2][2][64];  // [buf][tt][s][h][slot] 48 KB
    __shared__ float4 VB[3][2][2][2][64];  // [buf][rh][s][h][slot] 24 KB

    const int tid  = threadIdx.x;
    const int wave = tid >> 6;
    const int lane = tid & 63;
    const int r    = lane & 15;
    const int kg   = lane >> 4;

    const int t0    = blockIdx.x * 64;
    const int fbase = blockIdx.y * F;

    const float s_lo = S[r];
    const float s_hi = S[16 + r];

    // stage chunk c into buffer nb: 24 x 1KB instructions, 6 per wave
    auto stage = [&](int c, int nb) {
        const int fc = fbase + ((c + blockIdx.x) & (NCHK - 1)) * 64;
        #pragma unroll
        for (int t = 0; t < 6; ++t) {
            const int inst = wave * 6 + t;
            if (inst < 16) {            // X: tt, s, h
                const int tt = inst >> 2, s = (inst >> 1) & 1, h2 = inst & 1;
                gl_lds16(X + (size_t)(t0 + tt * 16 + r) * IN_F
                           + fc + s * 32 + h2 * 16 + kg * 4,
                         (void*)&XB[nb][tt][s][h2][0]);
            } else {                    // V: rh, s, h
                const int v = inst - 16;
                const int vr = v >> 2, s = (v >> 1) & 1, h2 = v & 1;
                gl_lds16(V + (size_t)(vr * 16 + r) * IN_F
                           + fc + s * 32 + h2 * 16 + kg * 4,
                         (void*)&VB[nb][vr][s][h2][0]);
            }
        }
    };

    const int h  = kg >> 1;             // 16-float half holding feats kg*8..+8
    const int qb = (kg & 1) * 2;

    f32x4 acc[2] = {};                  // rank halves for this wave's 16 tokens

    auto compute = [&](int cur) {
        #pragma unroll
        for (int s = 0; s < 2; ++s) {
            float4 x0 = *(const float4*)&XB[cur][wave][s][h][qb * 16 + r];
            float4 x1 = *(const float4*)&XB[cur][wave][s][h][(qb + 1) * 16 + r];
            bf16x8 xb = cvt8(x0, x1);
            #pragma unroll
            for (int rh = 0; rh < 2; ++rh) {
                float4 v0 = *(const float4*)&VB[cur][rh][s][h][qb * 16 + r];
                float4 v1 = *(const float4*)&VB[cur][rh][s][h][(qb + 1) * 16 + r];
                // A = X (m = token), B = V (n = rank-in-half)
                acc[rh] = __builtin_amdgcn_mfma_f32_16x16x32_bf16(
                              xb, cvt8(v0, v1), acc[rh], 0, 0, 0);
            }
        }
    };

    stage(0, 0);
    stage(1, 1);

    for (int c = 0; c < NCHK; ++c) {
        // stage BEFORE wait: buffer (c+2)%3's previous readers (chunk c-1)
        // finished before the trailing barrier of iter c-1 -> safe.
        if (c + 2 < NCHK) {
            stage(c + 2, (c + 2) % 3);
            asm volatile("s_waitcnt vmcnt(12)" ::: "memory");  // chunk c landed; c+1,c+2 in flight
        } else if (c + 1 < NCHK) {
            asm volatile("s_waitcnt vmcnt(6)" ::: "memory");
        } else {
            asm volatile("s_waitcnt vmcnt(0)" ::: "memory");
        }
        __builtin_amdgcn_s_barrier();
        __builtin_amdgcn_sched_barrier(0);
        compute(c % 3);
        __builtin_amdgcn_s_barrier();   // readers done before buf re-staged
    }

    // D: token = wave*16 + kg*4 + j, rank = rh*16 + r. Direct global store.
    float* Hq = Hpart + ((size_t)blockIdx.y * 8192 + t0) * RANK;
    #pragma unroll
    for (int j = 0; j < 4; ++j) {
        const int tok = wave * 16 + kg * 4 + j;
        Hq[(size_t)tok * RANK + r]      = acc[0][j] * s_lo;
        Hq[(size_t)tok * RANK + 16 + r] = acc[1][j] * s_hi;
    }
}

// ---------------- Kernel 1.5: H = sum_k Hpart[k] (4 MB -> 1 MB) ----------------
template <int NKS>
__global__ __launch_bounds__(256)
void lora_hred(const float* __restrict__ Hpart, float* __restrict__ H)
{
    const int idx = blockIdx.x * 256 + threadIdx.x;       // float4 index, 65536 total
    const float4* hp = reinterpret_cast<const float4*>(Hpart);
    float4 v = hp[idx];
    #pragma unroll
    for (int k = 1; k < NKS; ++k) {
        float4 p = hp[(size_t)k * 65536 + idx];
        v.x += p.x; v.y += p.y; v.z += p.z; v.w += p.w;
    }
    reinterpret_cast<float4*>(H)[idx] = v;
}

// ---------------- Kernel 2: Out = H @ U^T ----------------
// grid 4096, 256 thr. Block: 128 tokens x 64 cols; reads pre-reduced H
// (16 KB, L3-resident) instead of 4x16 KB partials.
__global__ __launch_bounds__(256, 4)
void lora_out(const float* __restrict__ H, const float* __restrict__ U,
              float* __restrict__ Out)
{
    __shared__ float Hs[128][33];

    const int tid  = threadIdx.x;
    const int wave = tid >> 6;
    const int lane = tid & 63;
    const int r    = lane & 15;
    const int kg   = lane >> 4;

    const int tt = blockIdx.x >> 6;
    const int cq = blockIdx.x & 63;
    const int t0 = tt * 128;
    const int c0 = cq * 64;

    float4 ua[4][2];
    #pragma unroll
    for (int b = 0; b < 4; ++b) {
        const float4* up = reinterpret_cast<const float4*>(
            U + (size_t)(c0 + b * 16 + r) * RANK + kg * 8);
        ua[b][0] = up[0];
        ua[b][1] = up[1];
    }

    const float4* hsrc = reinterpret_cast<const float4*>(H + (size_t)t0 * RANK);
    #pragma unroll
    for (int k4 = 0; k4 < 4; ++k4) {
        const int fidx = tid + k4 * 256;    // float4 idx within [128][32] tile
        float4 v = hsrc[fidx];
        const int tok = fidx >> 3;
        const int rr  = (fidx & 7) * 4;
        Hs[tok][rr] = v.x; Hs[tok][rr + 1] = v.y;
        Hs[tok][rr + 2] = v.z; Hs[tok][rr + 3] = v.w;
    }
    __syncthreads();

    bf16x8 ub[4];
    #pragma unroll
    for (int b = 0; b < 4; ++b) ub[b] = cvt8(ua[b][0], ua[b][1]);

    #pragma unroll
    for (int ai = 0; ai < 2; ++ai) {
        const int a = wave + ai * 4;
        bf16x8 hb;
        #pragma unroll
        for (int j = 0; j < 8; ++j) hb[j] = (__bf16)Hs[a * 16 + r][kg * 8 + j];
        float* orow = Out + (size_t)(t0 + a * 16 + r) * OUT_F + c0 + kg * 4;
        #pragma unroll
        for (int b = 0; b < 4; ++b) {
            f32x4 d = {0.f, 0.f, 0.f, 0.f};
            // A = U (m = outcol), B = H (n = token); D: lane j -> col kg*4+j
            d = __builtin_amdgcn_mfma_f32_16x16x32_bf16(ub[b], hb, d, 0, 0, 0);
            *reinterpret_cast<float4*>(orow + b * 16) = *reinterpret_cast<float4*>(&d);
        }
    }
}

extern "C" void kernel_launch(void* const* d_in, const int* in_sizes, int n_in,
                              void* d_out, int out_size, void* d_ws, size_t ws_size,
                              hipStream_t stream) {
    const float* X = (const float*)d_in[0];
    const float* U = (const float*)d_in[1];
    const float* S = (const float*)d_in[2];
    const float* V = (const float*)d_in[3];
    float* Out = (float*)d_out;

    float* H     = (float*)d_ws;                 // 1 MB reduced H
    float* Hpart = (float*)d_ws + 262144;        // 4 MB partials (KS=4)

    if (ws_size >= (size_t)5 * 1024 * 1024) {
        lora_h<4><<<dim3(128, 4), 256, 0, stream>>>(X, S, V, Hpart);
        lora_hred<4><<<256, 256, 0, stream>>>(Hpart, H);
        lora_out<<<4096, 256, 0, stream>>>(H, U, Out);
    } else {
        // KS=1: K1 writes final H directly (single partial), no reduce needed
        lora_h<1><<<dim3(128, 1), 256, 0, stream>>>(X, S, V, H);
        lora_out<<<4096, 256, 0, stream>>>(H, U, Out);
    }
}